// Round 4
// baseline (787.003 us; speedup 1.0000x reference)
//
#include <hip/hip_runtime.h>
#include <hip/hip_bf16.h>

// LSTM decoder: 12 steps, batch 32768, hidden 256, input 64, TF=1.
// One persistent block per 128 batch rows (256 blocks = 256 CUs).
// h double-buffered in LDS (bf16), c pinned in AGPRs (fp32, inline asm),
// W packed bf16 streamed from L2. TRANSPOSED mfma: D = W_frag @ h_frag
// so each lane owns 4 contiguous hidden units -> b64 conflict-free h-writes.

#define PRED_LEN 12
#define BATCH    32768
#define HID      256
#define IDIM     64
#define KTOT     320      // 256 (h) + 64 (x)
#define G4       1024     // 4*HID gate rows
#define BROWS    128      // batch rows per block
#define HSTR     264      // padded bf16 row stride for h in LDS (33 quads -> conflict-free b128)
#define XSTR     72       // padded bf16 row stride for x in LDS (9 quads)

#define DYN_LDS  ((2 * BROWS * HSTR + BROWS * XSTR) * 2)   // 153600 B

typedef short s16x8 __attribute__((ext_vector_type(8)));  // 8 x bf16 (MFMA frag)
typedef short s16x4 __attribute__((ext_vector_type(4)));
typedef float f32x4 __attribute__((ext_vector_type(4)));  // MFMA accum frag

static __device__ __forceinline__ float sigmoid_f(float x) {
    return 1.0f / (1.0f + __expf(-x));
}
static __device__ __forceinline__ float tanh_f(float x) {
    return 1.0f - 2.0f / (__expf(2.0f * x) + 1.0f);
}
static __device__ __forceinline__ unsigned short f2bf(float x) {
    __hip_bfloat16 h = __float2bfloat16(x);
    return *reinterpret_cast<unsigned short*>(&h);
}
static __device__ __forceinline__ float bf2f(unsigned short u) {
    __hip_bfloat16 h = *reinterpret_cast<__hip_bfloat16*>(&u);
    return __bfloat162float(h);
}

// Pin a value into the AGPR file (c-state storage): keeps the 64 persistent
// cell-state floats out of the VGPR side so nothing spills to scratch.
static __device__ __forceinline__ void ag_write(float& dst, float v) {
    asm("v_accvgpr_write_b32 %0, %1" : "=a"(dst) : "v"(v));
}
static __device__ __forceinline__ float ag_read(float src) {
    float r;
    asm("v_accvgpr_read_b32 %0, %1" : "=v"(r) : "a"(src));
    return r;
}

// Pack W = [W_hh | W_ih] as bf16 row-major [1024][320]; bcomb = b_ih + b_hh.
__global__ void prep_kernel(const float* __restrict__ W_ih,
                            const float* __restrict__ W_hh,
                            const float* __restrict__ b_ih,
                            const float* __restrict__ b_hh,
                            unsigned short* __restrict__ Wp,
                            float* __restrict__ bcomb) {
    int gid = blockIdx.x * 256 + threadIdx.x;
    if (gid < G4 * KTOT) {
        int n = gid / KTOT;
        int k = gid - n * KTOT;
        float v = (k < HID) ? W_hh[n * HID + k] : W_ih[n * IDIM + (k - HID)];
        Wp[gid] = f2bf(v);
    }
    if (gid < G4) bcomb[gid] = b_ih[gid] + b_hh[gid];
}

__global__ __launch_bounds__(512, 2) void lstm_kernel(
    const float* __restrict__ gr,      // (13, B, 2)
    const float* __restrict__ h0g,     // (B, 256)
    const unsigned short* __restrict__ Wp,   // (1024, 320) bf16
    const float* __restrict__ bcomb,   // (1024,)
    const float* __restrict__ W_hp,    // (2, 256)
    const float* __restrict__ b_hp,    // (2,)
    const float* __restrict__ W_emb,   // (64, 2)
    const float* __restrict__ b_emb,   // (64,)
    float* __restrict__ out)           // (12, B, 2)
{
    extern __shared__ unsigned short smem[];
    unsigned short* hb0 = smem;                        // [BROWS][HSTR]
    unsigned short* hb1 = smem + BROWS * HSTR;
    unsigned short* xb  = smem + 2 * BROWS * HSTR;     // [BROWS][XSTR]

    __shared__ float sWe0[IDIM], sWe1[IDIM], sBe[IDIM];
    __shared__ float sWhp[2 * HID];
    // per-wave transposed bias table: [wave][ch][g][u] u=lq*4+r (16)
    __shared__ float sBiasT[8 * 2 * 4 * 16];

    const int tid  = threadIdx.x;
    const int wave = tid >> 6;
    const int lane = tid & 63;
    const int l15  = lane & 15;
    const int lq   = lane >> 4;
    const int row0 = blockIdx.x * BROWS;

    if (tid < IDIM) {
        sWe0[tid] = W_emb[tid * 2 + 0];
        sWe1[tid] = W_emb[tid * 2 + 1];
        sBe[tid]  = b_emb[tid];
    }
    sWhp[tid] = W_hp[tid];   // blockDim 512 == 2*HID

    // stage transposed bias: value(w,ch,g,u) = bcomb[g*256 + ch*128 + w*16 + u]
#pragma unroll
    for (int j = tid; j < 8 * 2 * 4 * 16; j += 512) {
        int w   = j >> 7;
        int rem = j & 127;
        int ch  = rem >> 6;
        int g   = (rem >> 4) & 3;
        int u   = rem & 15;
        sBiasT[j] = bcomb[g * HID + ch * 128 + w * 16 + u];
    }

    const float bhp0 = b_hp[0];
    const float bhp1 = b_hp[1];

    // stage h0 (fp32 global -> bf16 LDS hb0)
#pragma unroll
    for (int j = 0; j < 16; ++j) {
        int idx = j * 2048 + tid * 4;
        const float4 v = *reinterpret_cast<const float4*>(&h0g[row0 * HID + idx]);
        int r = idx >> 8;
        int c = idx & 255;
        s16x4 pk;
        pk[0] = (short)f2bf(v.x); pk[1] = (short)f2bf(v.y);
        pk[2] = (short)f2bf(v.z); pk[3] = (short)f2bf(v.w);
        *reinterpret_cast<s16x4*>(&hb0[r * HSTR + c]) = pk;
    }

    // inline embedding: x[t] = gr[t+1] @ W_emb^T + b_emb  -> bf16 LDS
    auto stage_x = [&](int tt) {
        const int rr = tid >> 2;
        const int d0 = (tid & 3) * 16;
        const float2 g2 = *reinterpret_cast<const float2*>(
            &gr[(((size_t)(tt + 1)) * BATCH + row0 + rr) * 2]);
        s16x8 v0, v1;
#pragma unroll
        for (int e = 0; e < 8; ++e) {
            int d = d0 + e;
            v0[e] = (short)f2bf(g2.x * sWe0[d] + g2.y * sWe1[d] + sBe[d]);
        }
#pragma unroll
        for (int e = 0; e < 8; ++e) {
            int d = d0 + 8 + e;
            v1[e] = (short)f2bf(g2.x * sWe0[d] + g2.y * sWe1[d] + sBe[d]);
        }
        *reinterpret_cast<s16x8*>(&xb[rr * XSTR + d0])     = v0;
        *reinterpret_cast<s16x8*>(&xb[rr * XSTR + d0 + 8]) = v1;
    };

    __syncthreads();      // sWe*/h0/sBiasT visible
    stage_x(0);
    __syncthreads();

    // persistent cell state, fp32, PINNED in AGPRs. Index (ch*8+m)*4+r.
    float cst[64];
#pragma unroll
    for (int i = 0; i < 64; ++i) ag_write(cst[i], 0.0f);

    // per-lane bases (compile-time offsets elsewhere)
    const unsigned short* wb = Wp + (wave * 16 + l15) * KTOT + lq * 8;

    unsigned short* hread  = hb0;
    unsigned short* hwrite = hb1;

    for (int t = 0; t < PRED_LEN; ++t) {
        const unsigned short* hA = hread + l15 * HSTR + lq * 8;
        const unsigned short* xA = xb + l15 * XSTR + lq * 8;

#pragma unroll
        for (int ch = 0; ch < 2; ++ch) {
            // bias -> acc init (bias folded in; b4 regs die after init)
            f32x4 acc[8][4];
            {
                const float* bt = &sBiasT[(wave * 2 + ch) * 64 + lq * 4];
#pragma unroll
                for (int g = 0; g < 4; ++g) {
                    f32x4 b4 = *reinterpret_cast<const f32x4*>(&bt[g * 16]);
#pragma unroll
                    for (int m = 0; m < 8; ++m) acc[m][g] = b4;
                }
            }

#pragma unroll
            for (int kf = 0; kf < 10; ++kf) {
                s16x8 wfr[4];
#pragma unroll
                for (int g = 0; g < 4; ++g)
                    wfr[g] = *reinterpret_cast<const s16x8*>(
                        &wb[(g * HID + ch * 128) * KTOT + kf * 32]);
#pragma unroll
                for (int m = 0; m < 8; ++m) {
                    s16x8 afr;
                    if (kf < 8)
                        afr = *reinterpret_cast<const s16x8*>(
                            &hA[m * 16 * HSTR + kf * 32]);
                    else
                        afr = *reinterpret_cast<const s16x8*>(
                            &xA[m * 16 * XSTR + (kf - 8) * 32]);
                    // TRANSPOSED: A = weights, B = h -> D rows = units
#pragma unroll
                    for (int g = 0; g < 4; ++g)
                        acc[m][g] = __builtin_amdgcn_mfma_f32_16x16x32_bf16(
                            wfr[g], afr, acc[m][g], 0, 0, 0);
                }
            }

            // cell update: lane owns batch row (m*16+l15), units nbase+lq*4+r
            const int nbase = ch * 128 + wave * 16 + lq * 4;
#pragma unroll
            for (int m = 0; m < 8; ++m) {
                s16x4 hp;
#pragma unroll
                for (int r = 0; r < 4; ++r) {
                    float iv = acc[m][0][r];
                    float fv = acc[m][1][r];
                    float gv = acc[m][2][r];
                    float ov = acc[m][3][r];
                    float cold = ag_read(cst[(ch * 8 + m) * 4 + r]);
                    float cn = sigmoid_f(fv) * cold + sigmoid_f(iv) * tanh_f(gv);
                    ag_write(cst[(ch * 8 + m) * 4 + r], cn);
                    hp[r] = (short)f2bf(sigmoid_f(ov) * tanh_f(cn));
                }
                *reinterpret_cast<s16x4*>(
                    &hwrite[(m * 16 + l15) * HSTR + nbase]) = hp;
            }
        }
        __syncthreads();   // h_new complete; old h/x reads complete

        // out[t] = h_new @ W_hp^T + b_hp   (4 threads per row, shuffle-reduce)
        {
            const int rr = tid >> 2;
            const int q  = tid & 3;
            const unsigned short* hrow = &hwrite[rr * HSTR + q * 64];
            float s0 = 0.f, s1 = 0.f;
#pragma unroll
            for (int jj = 0; jj < 8; ++jj) {
                s16x8 hv = *reinterpret_cast<const s16x8*>(&hrow[jj * 8]);
#pragma unroll
                for (int e = 0; e < 8; ++e) {
                    float hf = bf2f((unsigned short)hv[e]);
                    int n = q * 64 + jj * 8 + e;
                    s0 += hf * sWhp[n];
                    s1 += hf * sWhp[HID + n];
                }
            }
            s0 += __shfl_xor(s0, 1); s0 += __shfl_xor(s0, 2);
            s1 += __shfl_xor(s1, 1); s1 += __shfl_xor(s1, 2);
            if (q == 0) {
                float2 o2 = make_float2(s0 + bhp0, s1 + bhp1);
                *reinterpret_cast<float2*>(&out[((size_t)t * BATCH + row0 + rr) * 2]) = o2;
            }
        }

        if (t + 1 < PRED_LEN) stage_x(t + 1);
        __syncthreads();   // x[t+1] staged; h_new reads (out proj) complete

        unsigned short* tmp = hread; hread = hwrite; hwrite = tmp;
    }
}

extern "C" void kernel_launch(void* const* d_in, const int* in_sizes, int n_in,
                              void* d_out, int out_size, void* d_ws, size_t ws_size,
                              hipStream_t stream) {
    const float* gr    = (const float*)d_in[0];
    const float* h0    = (const float*)d_in[1];
    const float* W_ih  = (const float*)d_in[2];
    const float* W_hh  = (const float*)d_in[3];
    const float* b_ih  = (const float*)d_in[4];
    const float* b_hh  = (const float*)d_in[5];
    const float* W_hp  = (const float*)d_in[6];
    const float* b_hp  = (const float*)d_in[7];
    const float* W_emb = (const float*)d_in[8];
    const float* b_emb = (const float*)d_in[9];
    float* out = (float*)d_out;

    unsigned short* Wp = (unsigned short*)d_ws;
    float* bcomb = (float*)((char*)d_ws + (size_t)G4 * KTOT * sizeof(unsigned short));

    prep_kernel<<<(G4 * KTOT) / 256, 256, 0, stream>>>(W_ih, W_hh, b_ih, b_hh, Wp, bcomb);

    (void)hipFuncSetAttribute((const void*)lstm_kernel,
                              hipFuncAttributeMaxDynamicSharedMemorySize, DYN_LDS);

    lstm_kernel<<<BATCH / BROWS, 512, DYN_LDS, stream>>>(
        gr, h0, Wp, bcomb, W_hp, b_hp, W_emb, b_emb, out);
}